// Round 12
// baseline (277.633 us; speedup 1.0000x reference)
//
#include <hip/hip_runtime.h>
#include <hip/hip_bf16.h>
#include <stdint.h>

#define B_ 2
#define L_ 2048
#define C_ 16
#define D_ 64
#define H_ 64
#define QBLK 128
#define KVBLK 64
#define NTILES 32            // L_/KVBLK
#define NTHREADS 512         // 8 waves = 4 q-waves x 2 kv-groups
#define NHEADS 32            // B_*C_
#define TILE_ELEMS 4096      // KVBLK*64 bf16 elements (8KB)
#define TENSOR_ELEMS (NHEADS * NTILES * TILE_ELEMS)  // 4,194,304

typedef __attribute__((ext_vector_type(8))) short bf16x8;
typedef __attribute__((ext_vector_type(16))) float f32x16;
typedef __attribute__((ext_vector_type(8))) unsigned short u16x8;

__device__ inline unsigned short f2bf(float f) {
  union { float f; unsigned int u; } v; v.f = f;
  unsigned int u = v.u;
  unsigned int r = (u + 0x7FFFu + ((u >> 16) & 1u)) >> 16;  // RNE
  return (unsigned short)r;
}

__device__ inline float fast_exp2(float x) {
#if __has_builtin(__builtin_amdgcn_exp2f)
  return __builtin_amdgcn_exp2f(x);
#else
  return exp2f(x);
#endif
}

__device__ inline unsigned cvt_pk_bf16(float lo, float hi) {
  unsigned r;
  asm("v_cvt_pk_bf16_f32 %0, %1, %2" : "=v"(r) : "v"(lo), "v"(hi));
  return r;
}

__device__ inline void pl32swap(unsigned &x, unsigned &y) {
#if __has_builtin(__builtin_amdgcn_permlane32_swap)
  auto r = __builtin_amdgcn_permlane32_swap(x, y, false, false);
  x = r[0]; y = r[1];
#else
  asm("v_permlane32_swap_b32 %0, %1" : "+v"(x), "+&v"(y));
#endif
}

__device__ inline float xsum32(float v) {
  unsigned x = __float_as_uint(v), y = x;
  pl32swap(x, y);
  return __uint_as_float(x) + __uint_as_float(y);
}

// ---------------- pre-pass ------------------------------------------------
// Both K and V in per-lane FRAGMENT order for direct global->reg MFMA loads:
//  Kb[head][t][frag=ks*2+half][lane][8]:
//      kv-row = half*32+(lane&31), k = ks*16+(lane>>5)*8+j   (j=0..7)
//  Vb[head][t][frag=m*2+half][lane][8]:
//      h-row  = half*32+(lane&31), kv = m*16+(lane>>5)*8+j
__global__ __launch_bounds__(256) void prepack_kernel(
    const float* __restrict__ Kg, const float* __restrict__ Vg,
    unsigned short* __restrict__ Kb, unsigned short* __restrict__ Vb) {
  int idx = blockIdx.x * 256 + threadIdx.x;     // 0 .. 2*524288-1
  if (idx < 524288) {
    int i = idx;
    int lane = i & 63, frag = (i >> 6) & 7, t = (i >> 9) & 31, head = i >> 14;
    int b = head >> 4, c = head & 15;
    int ks = frag >> 1, half = frag & 1;
    int row = half * 32 + (lane & 31);             // kv row
    int kb = ks * 16 + (lane >> 5) * 8;            // d offset
    const float* src = Kg + ((size_t)(b * L_ + t * 64 + row) * C_ + c) * D_ + kb;
    float4 a0 = ((const float4*)src)[0];
    float4 a1 = ((const float4*)src)[1];
    u16x8 pk;
    pk[0] = f2bf(a0.x); pk[1] = f2bf(a0.y); pk[2] = f2bf(a0.z); pk[3] = f2bf(a0.w);
    pk[4] = f2bf(a1.x); pk[5] = f2bf(a1.y); pk[6] = f2bf(a1.z); pk[7] = f2bf(a1.w);
    size_t dst = ((((size_t)(head * 32 + t)) * 8 + frag) * 64 + lane) * 8;
    *(u16x8*)&Kb[dst] = pk;
  } else {
    int i = idx - 524288;
    int lane = i & 63, frag = (i >> 6) & 7, t = (i >> 9) & 31, head = i >> 14;
    int b = head >> 4, c = head & 15;
    int m = frag >> 1, half = frag & 1;
    int h = half * 32 + (lane & 31);               // h row
    int kv0 = m * 16 + (lane >> 5) * 8;            // kv offset
    const float* src = Vg + ((size_t)(b * L_ + t * 64 + kv0) * C_ + c) * H_ + h;
    u16x8 pv;
#pragma unroll
    for (int j = 0; j < 8; ++j) pv[j] = f2bf(src[(size_t)j * C_ * H_]);
    size_t dst = ((((size_t)(head * 32 + t)) * 8 + frag) * 64 + lane) * 8;
    *(u16x8*)&Vb[dst] = pv;
  }
}

// 2-stage pipelined tile body, kv-stride 2 (this wave's tiles are T, T+2, ...).
// kf holds K(T+2) on entry, K(T+4) on exit; vf holds V(T) on entry, V(T+2) on exit.
#define TILE_BODY(SC0, SC1, SN0, SN1, T)                                          \
  {                                                                               \
    _Pragma("unroll")                                                             \
    for (int z = 0; z < 16; ++z) { SN0[z] = 0.f; SN1[z] = 0.f; }                  \
    float rst[4];                                                                 \
    bf16x8 pf[4];                                                                 \
    _Pragma("unroll")                                                             \
    for (int i = 0; i < 4; ++i) {                                                 \
      const int be = ((2 * i) & 3) * 4;                                           \
      const int bo = ((2 * i + 1) & 3) * 4;                                       \
      float p0[4], p1[4];                                                         \
      _Pragma("unroll")                                                           \
      for (int r = 0; r < 4; ++r) {                                               \
        float se = (i < 2) ? SC0[be + r] : SC1[be + r];                           \
        float so_ = (i < 2) ? SC0[bo + r] : SC1[bo + r];                          \
        p0[r] = fast_exp2(se);                                                    \
        p1[r] = fast_exp2(so_);                                                   \
      }                                                                           \
      rst[i] = ((p0[0] + p0[1]) + (p0[2] + p0[3])) +                              \
               ((p1[0] + p1[1]) + (p1[2] + p1[3]));                               \
      unsigned x0 = cvt_pk_bf16(p0[0], p0[1]);                                    \
      unsigned x1 = cvt_pk_bf16(p0[2], p0[3]);                                    \
      unsigned y0 = cvt_pk_bf16(p1[0], p1[1]);                                    \
      unsigned y1 = cvt_pk_bf16(p1[2], p1[3]);                                    \
      pl32swap(x0, y0);                                                           \
      pl32swap(x1, y1);                                                           \
      union { unsigned wd[4]; bf16x8 v; } pk_;                                    \
      pk_.wd[0] = x0; pk_.wd[1] = x1; pk_.wd[2] = y0; pk_.wd[3] = y1;             \
      pf[i] = pk_.v;                                                              \
      SN0 = __builtin_amdgcn_mfma_f32_32x32x16_bf16(kf[2 * i], qf[i], SN0, 0, 0, 0);     \
      SN1 = __builtin_amdgcn_mfma_f32_32x32x16_bf16(kf[2 * i + 1], qf[i], SN1, 0, 0, 0); \
    }                                                                             \
    l_own += (rst[0] + rst[1]) + (rst[2] + rst[3]);                               \
    {                                                                             \
      const int tk = ((T) + 4 < NTILES) ? (T) + 4 : (T);                          \
      _Pragma("unroll")                                                           \
      for (int f = 0; f < 8; ++f)                                                 \
        kf[f] = *(const bf16x8*)(KbL + (size_t)(tk * 8 + f) * 512);               \
    }                                                                             \
    __builtin_amdgcn_s_setprio(1);                                                \
    _Pragma("unroll")                                                             \
    for (int m = 0; m < 4; ++m) {                                                 \
      o0 = __builtin_amdgcn_mfma_f32_32x32x16_bf16(vf[2 * m], pf[m], o0, 0, 0, 0);       \
      o1 = __builtin_amdgcn_mfma_f32_32x32x16_bf16(vf[2 * m + 1], pf[m], o1, 0, 0, 0);   \
    }                                                                             \
    __builtin_amdgcn_s_setprio(0);                                                \
    {                                                                             \
      const int tv = ((T) + 2 < NTILES) ? (T) + 2 : (T);                          \
      _Pragma("unroll")                                                           \
      for (int f = 0; f < 8; ++f)                                                 \
        vf[f] = *(const bf16x8*)(VbL + (size_t)(tv * 8 + f) * 512);               \
    }                                                                             \
  }

// ------- flash fwd: in-block kv-split x2, reg K/V streams, 4 waves/SIMD ----
__global__ __launch_bounds__(NTHREADS, 4) void attn_fwd_kernel(
    const float* __restrict__ Qg,
    const unsigned short* __restrict__ Kb,
    const unsigned short* __restrict__ Vb,
    float* __restrict__ Og) {
  __shared__ float Osh[4 * 64 * 36];   // 36.9 KB merge scratch
  __shared__ float lsh[4 * 64];        // 1 KB

  const int tid  = threadIdx.x;
  const int lane = tid & 63;
  const int w    = tid >> 6;      // wave 0..7
  const int wq   = w & 3;         // q-wave: owns q-rows wq*32..+31
  const int g    = w >> 2;        // kv-group: 0 = even tiles, 1 = odd tiles
  const int ql   = lane & 31;
  const int u    = lane >> 5;

  const int bid   = blockIdx.x;
  const int swz   = (bid & 7) * 64 + (bid >> 3);   // XCD-contiguous
  const int head  = swz >> 4;     // 4 heads per XCD -> K/V L2-resident
  const int qtile = swz & 15;
  const int b     = head >> 4;
  const int c     = head & 15;
  const int q0    = qtile * QBLK;

  // per-lane fragment bases: frag f of tile t at base + (t*8+f)*512 elems
  const unsigned short* KbL = Kb + (size_t)head * NTILES * TILE_ELEMS + lane * 8;
  const unsigned short* VbL = Vb + (size_t)head * NTILES * TILE_ELEMS + lane * 8;

  // Q as B-operand, PRE-SCALED by 1/sqrt(D)*log2(e): col = ql, k = ks*16+u*8+j
  const float sc2 = 0.125f * 1.44269504088896340736f;
  const int qr = q0 + wq * 32 + ql;
  const float* qrow = Qg + ((size_t)(b * L_ + qr) * C_ + c) * D_;
  bf16x8 qf[4];
#pragma unroll
  for (int ks = 0; ks < 4; ++ks) {
    float4 a0 = *(const float4*)(qrow + ks * 16 + u * 8);
    float4 a1 = *(const float4*)(qrow + ks * 16 + u * 8 + 4);
    bf16x8 q8;
    q8[0] = (short)f2bf(a0.x * sc2); q8[1] = (short)f2bf(a0.y * sc2);
    q8[2] = (short)f2bf(a0.z * sc2); q8[3] = (short)f2bf(a0.w * sc2);
    q8[4] = (short)f2bf(a1.x * sc2); q8[5] = (short)f2bf(a1.y * sc2);
    q8[6] = (short)f2bf(a1.z * sc2); q8[7] = (short)f2bf(a1.w * sc2);
    qf[ks] = q8;
  }

  f32x16 o0, o1;   // O^T accumulators (unnormalized): h 0-31, 32-63
#pragma unroll
  for (int i = 0; i < 16; ++i) { o0[i] = 0.f; o1[i] = 0.f; }
  float l_own = 0.f;   // per-lane partial rowsum (this kv-group only)

  // prologue: K(g),V(g) -> regs; S(g) -> sA; then kf <- K(g+2)
  bf16x8 kf[8], vf[8];
#pragma unroll
  for (int f = 0; f < 8; ++f)
    kf[f] = *(const bf16x8*)(KbL + (size_t)(g * 8 + f) * 512);
#pragma unroll
  for (int f = 0; f < 8; ++f)
    vf[f] = *(const bf16x8*)(VbL + (size_t)(g * 8 + f) * 512);

  f32x16 sA0, sA1, sB0, sB1;
#pragma unroll
  for (int i = 0; i < 16; ++i) { sA0[i] = 0.f; sA1[i] = 0.f; }
  __builtin_amdgcn_s_setprio(1);
#pragma unroll
  for (int ks = 0; ks < 4; ++ks) {
    sA0 = __builtin_amdgcn_mfma_f32_32x32x16_bf16(kf[2 * ks], qf[ks], sA0, 0, 0, 0);
    sA1 = __builtin_amdgcn_mfma_f32_32x32x16_bf16(kf[2 * ks + 1], qf[ks], sA1, 0, 0, 0);
  }
  __builtin_amdgcn_s_setprio(0);
#pragma unroll
  for (int f = 0; f < 8; ++f)
    kf[f] = *(const bf16x8*)(KbL + (size_t)((g + 2) * 8 + f) * 512);   // K(g+2)

  // steady state: this wave's tiles g, g+2, ..., g+30 (16 tiles), 2x-unrolled
  for (int tt = 0; tt < 8; ++tt) {
    const int t = g + 4 * tt;
    TILE_BODY(sA0, sA1, sB0, sB1, t);
    TILE_BODY(sB0, sB1, sA0, sA1, t + 2);
  }

  // ---- merge kv-halves in LDS; g==0 waves normalize + store ----
  float l_all = xsum32(l_own);
  float* Ow = &Osh[(wq * 64 + lane) * 36];
  if (g == 1) {
#pragma unroll
    for (int rg = 0; rg < 4; ++rg) {
      float4 v0, v1;
      v0.x = o0[rg * 4 + 0]; v0.y = o0[rg * 4 + 1];
      v0.z = o0[rg * 4 + 2]; v0.w = o0[rg * 4 + 3];
      v1.x = o1[rg * 4 + 0]; v1.y = o1[rg * 4 + 1];
      v1.z = o1[rg * 4 + 2]; v1.w = o1[rg * 4 + 3];
      *(float4*)(Ow + rg * 4) = v0;
      *(float4*)(Ow + 16 + rg * 4) = v1;
    }
    lsh[wq * 64 + lane] = l_all;
  }
  __syncthreads();
  if (g == 0) {
    const float inv = 1.0f / (l_all + lsh[wq * 64 + lane]);
    float* orow = Og + ((size_t)(b * L_ + qr) * C_ + c) * H_;
#pragma unroll
    for (int rg = 0; rg < 4; ++rg) {
      float4 a0 = *(const float4*)(Ow + rg * 4);
      float4 a1 = *(const float4*)(Ow + 16 + rg * 4);
      float4 v0, v1;
      v0.x = (o0[rg * 4 + 0] + a0.x) * inv; v0.y = (o0[rg * 4 + 1] + a0.y) * inv;
      v0.z = (o0[rg * 4 + 2] + a0.z) * inv; v0.w = (o0[rg * 4 + 3] + a0.w) * inv;
      v1.x = (o1[rg * 4 + 0] + a1.x) * inv; v1.y = (o1[rg * 4 + 1] + a1.y) * inv;
      v1.z = (o1[rg * 4 + 2] + a1.z) * inv; v1.w = (o1[rg * 4 + 3] + a1.w) * inv;
      *(float4*)(orow + 8 * rg + 4 * u) = v0;
      *(float4*)(orow + 32 + 8 * rg + 4 * u) = v1;
    }
  }
}

extern "C" void kernel_launch(void* const* d_in, const int* in_sizes, int n_in,
                              void* d_out, int out_size, void* d_ws, size_t ws_size,
                              hipStream_t stream) {
  const float* Qg = (const float*)d_in[0];
  const float* Kg = (const float*)d_in[1];
  const float* Vg = (const float*)d_in[2];
  float* Og = (float*)d_out;

  unsigned short* Kb = (unsigned short*)d_ws;
  unsigned short* Vb = Kb + (size_t)TENSOR_ELEMS;

  prepack_kernel<<<4096, 256, 0, stream>>>(Kg, Vg, Kb, Vb);

  dim3 grid(NHEADS * (L_ / QBLK));   // 512 blocks of 8 waves -> 4 waves/SIMD
  dim3 block(NTHREADS);
  attn_fwd_kernel<<<grid, block, 0, stream>>>(Qg, Kb, Vb, Og);
}

// Round 13
// 75.404 us; speedup vs baseline: 3.6819x; 3.6819x over previous
//
#include <hip/hip_runtime.h>
#include <hip/hip_bf16.h>
#include <stdint.h>

#define B_ 2
#define L_ 2048
#define C_ 16
#define D_ 64
#define H_ 64
#define QBLK 128
#define KVBLK 64
#define NTILES 32            // L_/KVBLK
#define NTHREADS 256         // 4 waves = 2 q-positions(64 rows) x 2 kv-groups
#define NHEADS 32            // B_*C_
#define TILE_ELEMS 4096      // KVBLK*64 bf16 elements (8KB)
#define TENSOR_ELEMS (NHEADS * NTILES * TILE_ELEMS)  // 4,194,304

typedef __attribute__((ext_vector_type(8))) short bf16x8;
typedef __attribute__((ext_vector_type(16))) float f32x16;
typedef __attribute__((ext_vector_type(8))) unsigned short u16x8;

__device__ inline unsigned short f2bf(float f) {
  union { float f; unsigned int u; } v; v.f = f;
  unsigned int u = v.u;
  unsigned int r = (u + 0x7FFFu + ((u >> 16) & 1u)) >> 16;  // RNE
  return (unsigned short)r;
}

__device__ inline float fast_exp2(float x) {
#if __has_builtin(__builtin_amdgcn_exp2f)
  return __builtin_amdgcn_exp2f(x);
#else
  return exp2f(x);
#endif
}

__device__ inline unsigned cvt_pk_bf16(float lo, float hi) {
  unsigned r;
  asm("v_cvt_pk_bf16_f32 %0, %1, %2" : "=v"(r) : "v"(lo), "v"(hi));
  return r;
}

__device__ inline void pl32swap(unsigned &x, unsigned &y) {
#if __has_builtin(__builtin_amdgcn_permlane32_swap)
  auto r = __builtin_amdgcn_permlane32_swap(x, y, false, false);
  x = r[0]; y = r[1];
#else
  asm("v_permlane32_swap_b32 %0, %1" : "+v"(x), "+&v"(y));
#endif
}

__device__ inline float xsum32(float v) {
  unsigned x = __float_as_uint(v), y = x;
  pl32swap(x, y);
  return __uint_as_float(x) + __uint_as_float(y);
}

// ---------------- pre-pass ------------------------------------------------
// Both K and V in per-lane FRAGMENT order for direct global->reg MFMA loads:
//  Kb[head][t][frag=ks*2+half][lane][8]:
//      kv-row = half*32+(lane&31), k = ks*16+(lane>>5)*8+j   (j=0..7)
//  Vb[head][t][frag=m*2+half][lane][8]:
//      h-row  = half*32+(lane&31), kv = m*16+(lane>>5)*8+j
__global__ __launch_bounds__(256) void prepack_kernel(
    const float* __restrict__ Kg, const float* __restrict__ Vg,
    unsigned short* __restrict__ Kb, unsigned short* __restrict__ Vb) {
  int idx = blockIdx.x * 256 + threadIdx.x;     // 0 .. 2*524288-1
  if (idx < 524288) {
    int i = idx;
    int lane = i & 63, frag = (i >> 6) & 7, t = (i >> 9) & 31, head = i >> 14;
    int b = head >> 4, c = head & 15;
    int ks = frag >> 1, half = frag & 1;
    int row = half * 32 + (lane & 31);             // kv row
    int kb = ks * 16 + (lane >> 5) * 8;            // d offset
    const float* src = Kg + ((size_t)(b * L_ + t * 64 + row) * C_ + c) * D_ + kb;
    float4 a0 = ((const float4*)src)[0];
    float4 a1 = ((const float4*)src)[1];
    u16x8 pk;
    pk[0] = f2bf(a0.x); pk[1] = f2bf(a0.y); pk[2] = f2bf(a0.z); pk[3] = f2bf(a0.w);
    pk[4] = f2bf(a1.x); pk[5] = f2bf(a1.y); pk[6] = f2bf(a1.z); pk[7] = f2bf(a1.w);
    size_t dst = ((((size_t)(head * 32 + t)) * 8 + frag) * 64 + lane) * 8;
    *(u16x8*)&Kb[dst] = pk;
  } else {
    int i = idx - 524288;
    int lane = i & 63, frag = (i >> 6) & 7, t = (i >> 9) & 31, head = i >> 14;
    int b = head >> 4, c = head & 15;
    int m = frag >> 1, half = frag & 1;
    int h = half * 32 + (lane & 31);               // h row
    int kv0 = m * 16 + (lane >> 5) * 8;            // kv offset
    const float* src = Vg + ((size_t)(b * L_ + t * 64 + kv0) * C_ + c) * H_ + h;
    u16x8 pv;
#pragma unroll
    for (int j = 0; j < 8; ++j) pv[j] = f2bf(src[(size_t)j * C_ * H_]);
    size_t dst = ((((size_t)(head * 32 + t)) * 8 + frag) * 64 + lane) * 8;
    *(u16x8*)&Vb[dst] = pv;
  }
}

// One q-group's work for tile T. kf/vf are shared across both groups.
// IS_LAST=1 (group 1): refill kf after QK, vf after PV (stride-2 tiles).
#define GROUP_BODY(OH0, OH1, QF, LWN, IS_LAST, T)                                 \
  {                                                                               \
    f32x16 s0, s1;                                                                \
    _Pragma("unroll")                                                             \
    for (int z = 0; z < 16; ++z) { s0[z] = 0.f; s1[z] = 0.f; }                    \
    __builtin_amdgcn_s_setprio(1);                                                \
    _Pragma("unroll")                                                             \
    for (int ks = 0; ks < 4; ++ks) {                                              \
      s0 = __builtin_amdgcn_mfma_f32_32x32x16_bf16(kf[2 * ks], QF[ks], s0, 0, 0, 0);     \
      s1 = __builtin_amdgcn_mfma_f32_32x32x16_bf16(kf[2 * ks + 1], QF[ks], s1, 0, 0, 0); \
    }                                                                             \
    __builtin_amdgcn_s_setprio(0);                                                \
    if (IS_LAST) {                                                                \
      const int tk = ((T) + 2 < NTILES) ? (T) + 2 : (T);                          \
      _Pragma("unroll")                                                           \
      for (int f = 0; f < 8; ++f)                                                 \
        kf[f] = *(const bf16x8*)(KbL + (size_t)(tk * 8 + f) * 512);               \
    }                                                                             \
    float rst[4];                                                                 \
    bf16x8 pf[4];                                                                 \
    _Pragma("unroll")                                                             \
    for (int tq = 0; tq < 4; ++tq) {                                              \
      const int be = ((2 * tq) & 3) * 4;                                          \
      const int bo = ((2 * tq + 1) & 3) * 4;                                      \
      float p0[4], p1[4];                                                         \
      _Pragma("unroll")                                                           \
      for (int r = 0; r < 4; ++r) {                                               \
        float se = (tq < 2) ? s0[be + r] : s1[be + r];                            \
        float so_ = (tq < 2) ? s0[bo + r] : s1[bo + r];                           \
        p0[r] = fast_exp2(se);                                                    \
        p1[r] = fast_exp2(so_);                                                   \
      }                                                                           \
      rst[tq] = ((p0[0] + p0[1]) + (p0[2] + p0[3])) +                             \
                ((p1[0] + p1[1]) + (p1[2] + p1[3]));                              \
      unsigned x0 = cvt_pk_bf16(p0[0], p0[1]);                                    \
      unsigned x1 = cvt_pk_bf16(p0[2], p0[3]);                                    \
      unsigned y0 = cvt_pk_bf16(p1[0], p1[1]);                                    \
      unsigned y1 = cvt_pk_bf16(p1[2], p1[3]);                                    \
      pl32swap(x0, y0);                                                           \
      pl32swap(x1, y1);                                                           \
      union { unsigned wd[4]; bf16x8 v; } pk_;                                    \
      pk_.wd[0] = x0; pk_.wd[1] = x1; pk_.wd[2] = y0; pk_.wd[3] = y1;             \
      pf[tq] = pk_.v;                                                             \
    }                                                                             \
    LWN += (rst[0] + rst[1]) + (rst[2] + rst[3]);                                 \
    __builtin_amdgcn_s_setprio(1);                                                \
    _Pragma("unroll")                                                             \
    for (int m = 0; m < 4; ++m) {                                                 \
      OH0 = __builtin_amdgcn_mfma_f32_32x32x16_bf16(vf[2 * m], pf[m], OH0, 0, 0, 0);     \
      OH1 = __builtin_amdgcn_mfma_f32_32x32x16_bf16(vf[2 * m + 1], pf[m], OH1, 0, 0, 0); \
    }                                                                             \
    __builtin_amdgcn_s_setprio(0);                                                \
    if (IS_LAST) {                                                                \
      const int tv = ((T) + 2 < NTILES) ? (T) + 2 : (T);                          \
      _Pragma("unroll")                                                           \
      for (int f = 0; f < 8; ++f)                                                 \
        vf[f] = *(const bf16x8*)(VbL + (size_t)(tv * 8 + f) * 512);               \
    }                                                                             \
  }

// --- flash fwd: 64 q-rows/wave (2 groups share K/V frags), kv-split x2 -----
__global__ __launch_bounds__(NTHREADS, 2) void attn_fwd_kernel(
    const float* __restrict__ Qg,
    const unsigned short* __restrict__ Kb,
    const unsigned short* __restrict__ Vb,
    float* __restrict__ Og) {
  __shared__ float Osh[2 * 64 * 68];   // 34.8 KB merge scratch (stride-68 pad)
  __shared__ float lsh[2 * 2 * 64];    // per (qw, group, lane)

  const int tid  = threadIdx.x;
  const int lane = tid & 63;
  const int w    = tid >> 6;      // wave 0..3
  const int qw   = w >> 1;        // q-position 0..1 (64 rows each)
  const int g    = w & 1;         // kv-group: 0 = even tiles, 1 = odd tiles
  const int ql   = lane & 31;
  const int u    = lane >> 5;

  const int bid   = blockIdx.x;
  const int swz   = (bid & 7) * 64 + (bid >> 3);   // XCD-contiguous
  const int head  = swz >> 4;     // 4 heads per XCD -> K/V L2-resident
  const int qtile = swz & 15;
  const int b     = head >> 4;
  const int c     = head & 15;
  const int q0    = qtile * QBLK + qw * 64;

  // per-lane fragment bases: frag f of tile t at base + (t*8+f)*512 elems
  const unsigned short* KbL = Kb + (size_t)head * NTILES * TILE_ELEMS + lane * 8;
  const unsigned short* VbL = Vb + (size_t)head * NTILES * TILE_ELEMS + lane * 8;

  // Q as B-operand, PRE-SCALED by 1/sqrt(D)*log2(e); 2 groups of 32 q-rows
  const float sc2 = 0.125f * 1.44269504088896340736f;
  bf16x8 qf0[4], qf1[4];
#pragma unroll
  for (int h = 0; h < 2; ++h) {
    const int qr = q0 + h * 32 + ql;
    const float* qrow = Qg + ((size_t)(b * L_ + qr) * C_ + c) * D_;
#pragma unroll
    for (int ks = 0; ks < 4; ++ks) {
      float4 a0 = *(const float4*)(qrow + ks * 16 + u * 8);
      float4 a1 = *(const float4*)(qrow + ks * 16 + u * 8 + 4);
      bf16x8 q8;
      q8[0] = (short)f2bf(a0.x * sc2); q8[1] = (short)f2bf(a0.y * sc2);
      q8[2] = (short)f2bf(a0.z * sc2); q8[3] = (short)f2bf(a0.w * sc2);
      q8[4] = (short)f2bf(a1.x * sc2); q8[5] = (short)f2bf(a1.y * sc2);
      q8[6] = (short)f2bf(a1.z * sc2); q8[7] = (short)f2bf(a1.w * sc2);
      if (h == 0) qf0[ks] = q8; else qf1[ks] = q8;
    }
  }

  f32x16 o00, o01, o10, o11;   // O^T acc per group x h-block (unnormalized)
#pragma unroll
  for (int i = 0; i < 16; ++i) { o00[i] = 0.f; o01[i] = 0.f; o10[i] = 0.f; o11[i] = 0.f; }
  float l0 = 0.f, l1 = 0.f;

  // prologue: this kv-group's first tile straight into registers
  bf16x8 kf[8], vf[8];
#pragma unroll
  for (int f = 0; f < 8; ++f)
    kf[f] = *(const bf16x8*)(KbL + (size_t)(g * 8 + f) * 512);
#pragma unroll
  for (int f = 0; f < 8; ++f)
    vf[f] = *(const bf16x8*)(VbL + (size_t)(g * 8 + f) * 512);

  // steady state: tiles g, g+2, ..., g+30; both q-groups share kf/vf
  for (int tt = 0; tt < NTILES / 2; ++tt) {
    const int t = g + 2 * tt;
    GROUP_BODY(o00, o01, qf0, l0, 0, t);
    GROUP_BODY(o10, o11, qf1, l1, 1, t);
  }

  // ---- merge kv-halves in LDS; g==0 waves normalize + store ----
  float la0 = xsum32(l0), la1 = xsum32(l1);
  float* Ow = &Osh[(qw * 64 + lane) * 68];
  if (g == 1) {
#pragma unroll
    for (int rg = 0; rg < 4; ++rg) {
      *(float4*)(Ow + rg * 4)      = (float4){o00[rg*4+0], o00[rg*4+1], o00[rg*4+2], o00[rg*4+3]};
      *(float4*)(Ow + 16 + rg * 4) = (float4){o01[rg*4+0], o01[rg*4+1], o01[rg*4+2], o01[rg*4+3]};
      *(float4*)(Ow + 32 + rg * 4) = (float4){o10[rg*4+0], o10[rg*4+1], o10[rg*4+2], o10[rg*4+3]};
      *(float4*)(Ow + 48 + rg * 4) = (float4){o11[rg*4+0], o11[rg*4+1], o11[rg*4+2], o11[rg*4+3]};
    }
    lsh[(qw * 2 + 0) * 64 + lane] = la0;
    lsh[(qw * 2 + 1) * 64 + lane] = la1;
  }
  __syncthreads();
  if (g == 0) {
    const float inv0 = 1.0f / (la0 + lsh[(qw * 2 + 0) * 64 + lane]);
    const float inv1 = 1.0f / (la1 + lsh[(qw * 2 + 1) * 64 + lane]);
    const int qr0 = q0 + ql;
    const int qr1 = q0 + 32 + ql;
    float* orow0 = Og + ((size_t)(b * L_ + qr0) * C_ + c) * H_;
    float* orow1 = Og + ((size_t)(b * L_ + qr1) * C_ + c) * H_;
#pragma unroll
    for (int rg = 0; rg < 4; ++rg) {
      float4 a0 = *(const float4*)(Ow + rg * 4);
      float4 a1 = *(const float4*)(Ow + 16 + rg * 4);
      float4 a2 = *(const float4*)(Ow + 32 + rg * 4);
      float4 a3 = *(const float4*)(Ow + 48 + rg * 4);
      float4 v0, v1, v2, v3;
      v0.x = (o00[rg*4+0] + a0.x) * inv0; v0.y = (o00[rg*4+1] + a0.y) * inv0;
      v0.z = (o00[rg*4+2] + a0.z) * inv0; v0.w = (o00[rg*4+3] + a0.w) * inv0;
      v1.x = (o01[rg*4+0] + a1.x) * inv0; v1.y = (o01[rg*4+1] + a1.y) * inv0;
      v1.z = (o01[rg*4+2] + a1.z) * inv0; v1.w = (o01[rg*4+3] + a1.w) * inv0;
      v2.x = (o10[rg*4+0] + a2.x) * inv1; v2.y = (o10[rg*4+1] + a2.y) * inv1;
      v2.z = (o10[rg*4+2] + a2.z) * inv1; v2.w = (o10[rg*4+3] + a2.w) * inv1;
      v3.x = (o11[rg*4+0] + a3.x) * inv1; v3.y = (o11[rg*4+1] + a3.y) * inv1;
      v3.z = (o11[rg*4+2] + a3.z) * inv1; v3.w = (o11[rg*4+3] + a3.w) * inv1;
      *(float4*)(orow0 + 8 * rg + 4 * u) = v0;
      *(float4*)(orow0 + 32 + 8 * rg + 4 * u) = v1;
      *(float4*)(orow1 + 8 * rg + 4 * u) = v2;
      *(float4*)(orow1 + 32 + 8 * rg + 4 * u) = v3;
    }
  }
}

extern "C" void kernel_launch(void* const* d_in, const int* in_sizes, int n_in,
                              void* d_out, int out_size, void* d_ws, size_t ws_size,
                              hipStream_t stream) {
  const float* Qg = (const float*)d_in[0];
  const float* Kg = (const float*)d_in[1];
  const float* Vg = (const float*)d_in[2];
  float* Og = (float*)d_out;

  unsigned short* Kb = (unsigned short*)d_ws;
  unsigned short* Vb = Kb + (size_t)TENSOR_ELEMS;

  prepack_kernel<<<4096, 256, 0, stream>>>(Kg, Vg, Kb, Vb);

  dim3 grid(NHEADS * (L_ / QBLK));   // 512 blocks of 4 waves, 2 blocks/CU
  dim3 block(NTHREADS);
  attn_fwd_kernel<<<grid, block, 0, stream>>>(Qg, Kb, Vb, Og);
}

// Round 14
// 64.889 us; speedup vs baseline: 4.2786x; 1.1621x over previous
//
#include <hip/hip_runtime.h>
#include <hip/hip_bf16.h>
#include <stdint.h>

#define B_ 2
#define L_ 2048
#define C_ 16
#define D_ 64
#define H_ 64
#define QBLK 128
#define KVBLK 64
#define NTILES 32            // L_/KVBLK
#define NTHREADS 256         // 4 waves = 2 q-positions(64 rows) x 2 kv-groups
#define NHEADS 32            // B_*C_
#define TILE_ELEMS 4096      // KVBLK*64 bf16 elements (8KB)
#define TENSOR_ELEMS (NHEADS * NTILES * TILE_ELEMS)  // 4,194,304

typedef __attribute__((ext_vector_type(8))) short bf16x8;
typedef __attribute__((ext_vector_type(16))) float f32x16;
typedef __attribute__((ext_vector_type(8))) unsigned short u16x8;

__device__ inline unsigned short f2bf(float f) {
  union { float f; unsigned int u; } v; v.f = f;
  unsigned int u = v.u;
  unsigned int r = (u + 0x7FFFu + ((u >> 16) & 1u)) >> 16;  // RNE
  return (unsigned short)r;
}

__device__ inline float fast_exp2(float x) {
#if __has_builtin(__builtin_amdgcn_exp2f)
  return __builtin_amdgcn_exp2f(x);
#else
  return exp2f(x);
#endif
}

__device__ inline unsigned cvt_pk_bf16(float lo, float hi) {
  unsigned r;
  asm("v_cvt_pk_bf16_f32 %0, %1, %2" : "=v"(r) : "v"(lo), "v"(hi));
  return r;
}

__device__ inline void pl32swap(unsigned &x, unsigned &y) {
#if __has_builtin(__builtin_amdgcn_permlane32_swap)
  auto r = __builtin_amdgcn_permlane32_swap(x, y, false, false);
  x = r[0]; y = r[1];
#else
  asm("v_permlane32_swap_b32 %0, %1" : "+v"(x), "+&v"(y));
#endif
}

__device__ inline float xsum32(float v) {
  unsigned x = __float_as_uint(v), y = x;
  pl32swap(x, y);
  return __uint_as_float(x) + __uint_as_float(y);
}

// ---------------- pre-pass ------------------------------------------------
// Both K and V in per-lane FRAGMENT order for direct global->reg MFMA loads:
//  Kb[head][t][frag=ks*2+half][lane][8]:
//      kv-row = half*32+(lane&31), k = ks*16+(lane>>5)*8+j   (j=0..7)
//  Vb[head][t][frag=m*2+half][lane][8]:
//      h-row  = half*32+(lane&31), kv = m*16+(lane>>5)*8+j
__global__ __launch_bounds__(256) void prepack_kernel(
    const float* __restrict__ Kg, const float* __restrict__ Vg,
    unsigned short* __restrict__ Kb, unsigned short* __restrict__ Vb) {
  int idx = blockIdx.x * 256 + threadIdx.x;     // 0 .. 2*524288-1
  if (idx < 524288) {
    int i = idx;
    int lane = i & 63, frag = (i >> 6) & 7, t = (i >> 9) & 31, head = i >> 14;
    int b = head >> 4, c = head & 15;
    int ks = frag >> 1, half = frag & 1;
    int row = half * 32 + (lane & 31);             // kv row
    int kb = ks * 16 + (lane >> 5) * 8;            // d offset
    const float* src = Kg + ((size_t)(b * L_ + t * 64 + row) * C_ + c) * D_ + kb;
    float4 a0 = ((const float4*)src)[0];
    float4 a1 = ((const float4*)src)[1];
    u16x8 pk;
    pk[0] = f2bf(a0.x); pk[1] = f2bf(a0.y); pk[2] = f2bf(a0.z); pk[3] = f2bf(a0.w);
    pk[4] = f2bf(a1.x); pk[5] = f2bf(a1.y); pk[6] = f2bf(a1.z); pk[7] = f2bf(a1.w);
    size_t dst = ((((size_t)(head * 32 + t)) * 8 + frag) * 64 + lane) * 8;
    *(u16x8*)&Kb[dst] = pk;
  } else {
    int i = idx - 524288;
    int lane = i & 63, frag = (i >> 6) & 7, t = (i >> 9) & 31, head = i >> 14;
    int b = head >> 4, c = head & 15;
    int m = frag >> 1, half = frag & 1;
    int h = half * 32 + (lane & 31);               // h row
    int kv0 = m * 16 + (lane >> 5) * 8;            // kv offset
    const float* src = Vg + ((size_t)(b * L_ + t * 64 + kv0) * C_ + c) * H_ + h;
    u16x8 pv;
#pragma unroll
    for (int j = 0; j < 8; ++j) pv[j] = f2bf(src[(size_t)j * C_ * H_]);
    size_t dst = ((((size_t)(head * 32 + t)) * 8 + frag) * 64 + lane) * 8;
    *(u16x8*)&Vb[dst] = pv;
  }
}

// softmax(S0,S1) -> pf, accumulate rowsum into L, then PV into O0,O1.
// vc00..vc13 are the tile's 8 V fragments (shared by both q-groups).
#define SM_PV(S0, S1, O0, O1, L)                                                  \
  {                                                                               \
    float rst[4];                                                                 \
    bf16x8 pf[4];                                                                 \
    _Pragma("unroll")                                                             \
    for (int tq = 0; tq < 4; ++tq) {                                              \
      const int be = ((2 * tq) & 3) * 4;                                          \
      const int bo = ((2 * tq + 1) & 3) * 4;                                      \
      float p0[4], p1[4];                                                         \
      _Pragma("unroll")                                                           \
      for (int r = 0; r < 4; ++r) {                                               \
        float se = (tq < 2) ? S0[be + r] : S1[be + r];                            \
        float so_ = (tq < 2) ? S0[bo + r] : S1[bo + r];                           \
        p0[r] = fast_exp2(se);                                                    \
        p1[r] = fast_exp2(so_);                                                   \
      }                                                                           \
      rst[tq] = ((p0[0] + p0[1]) + (p0[2] + p0[3])) +                             \
                ((p1[0] + p1[1]) + (p1[2] + p1[3]));                              \
      unsigned x0 = cvt_pk_bf16(p0[0], p0[1]);                                    \
      unsigned x1 = cvt_pk_bf16(p0[2], p0[3]);                                    \
      unsigned y0 = cvt_pk_bf16(p1[0], p1[1]);                                    \
      unsigned y1 = cvt_pk_bf16(p1[2], p1[3]);                                    \
      pl32swap(x0, y0);                                                           \
      pl32swap(x1, y1);                                                           \
      union { unsigned wd[4]; bf16x8 v; } pk_;                                    \
      pk_.wd[0] = x0; pk_.wd[1] = x1; pk_.wd[2] = y0; pk_.wd[3] = y1;             \
      pf[tq] = pk_.v;                                                             \
    }                                                                             \
    L += (rst[0] + rst[1]) + (rst[2] + rst[3]);                                   \
    __builtin_amdgcn_s_setprio(1);                                                \
    O0 = __builtin_amdgcn_mfma_f32_32x32x16_bf16(vc00, pf[0], O0, 0, 0, 0);       \
    O1 = __builtin_amdgcn_mfma_f32_32x32x16_bf16(vc01, pf[0], O1, 0, 0, 0);       \
    O0 = __builtin_amdgcn_mfma_f32_32x32x16_bf16(vc02, pf[1], O0, 0, 0, 0);       \
    O1 = __builtin_amdgcn_mfma_f32_32x32x16_bf16(vc03, pf[1], O1, 0, 0, 0);       \
    O0 = __builtin_amdgcn_mfma_f32_32x32x16_bf16(vc10, pf[2], O0, 0, 0, 0);       \
    O1 = __builtin_amdgcn_mfma_f32_32x32x16_bf16(vc11, pf[2], O1, 0, 0, 0);       \
    O0 = __builtin_amdgcn_mfma_f32_32x32x16_bf16(vc12, pf[3], O0, 0, 0, 0);       \
    O1 = __builtin_amdgcn_mfma_f32_32x32x16_bf16(vc13, pf[3], O1, 0, 0, 0);       \
    __builtin_amdgcn_s_setprio(0);                                                \
  }

// --- flash fwd: 64 q-rows/wave share K/V frags x2, kv-split x2, chunked ----
__global__ __launch_bounds__(NTHREADS, 2) void attn_fwd_kernel(
    const float* __restrict__ Qg,
    const unsigned short* __restrict__ Kb,
    const unsigned short* __restrict__ Vb,
    float* __restrict__ Og) {
  __shared__ float Osh[2 * 64 * 68];   // 34.8 KB merge scratch
  __shared__ float lsh[2 * 2 * 64];

  const int tid  = threadIdx.x;
  const int lane = tid & 63;
  const int w    = tid >> 6;      // wave 0..3
  const int qw   = w >> 1;        // q-position 0..1 (64 rows each)
  const int g    = w & 1;         // kv-group: 0 = even tiles, 1 = odd tiles
  const int ql   = lane & 31;
  const int u    = lane >> 5;

  const int bid   = blockIdx.x;
  const int swz   = (bid & 7) * 64 + (bid >> 3);   // XCD-contiguous
  const int head  = swz >> 4;     // 4 heads per XCD -> K/V L2-resident
  const int qtile = swz & 15;
  const int b     = head >> 4;
  const int c     = head & 15;
  const int q0    = qtile * QBLK + qw * 64;

  const unsigned short* KbL = Kb + (size_t)head * NTILES * TILE_ELEMS + lane * 8;
  const unsigned short* VbL = Vb + (size_t)head * NTILES * TILE_ELEMS + lane * 8;

  // Q as B-operand, PRE-SCALED by 1/sqrt(D)*log2(e); 2 groups of 32 q-rows
  const float sc2 = 0.125f * 1.44269504088896340736f;
  bf16x8 qf0[4], qf1[4];
#pragma unroll
  for (int h = 0; h < 2; ++h) {
    const int qr = q0 + h * 32 + ql;
    const float* qrow = Qg + ((size_t)(b * L_ + qr) * C_ + c) * D_;
#pragma unroll
    for (int ks = 0; ks < 4; ++ks) {
      float4 a0 = *(const float4*)(qrow + ks * 16 + u * 8);
      float4 a1 = *(const float4*)(qrow + ks * 16 + u * 8 + 4);
      bf16x8 q8;
      q8[0] = (short)f2bf(a0.x * sc2); q8[1] = (short)f2bf(a0.y * sc2);
      q8[2] = (short)f2bf(a0.z * sc2); q8[3] = (short)f2bf(a0.w * sc2);
      q8[4] = (short)f2bf(a1.x * sc2); q8[5] = (short)f2bf(a1.y * sc2);
      q8[6] = (short)f2bf(a1.z * sc2); q8[7] = (short)f2bf(a1.w * sc2);
      if (h == 0) qf0[ks] = q8; else qf1[ks] = q8;
    }
  }

  f32x16 o00, o01, o10, o11;   // O^T acc per group x h-block (AGPR side)
#pragma unroll
  for (int i = 0; i < 16; ++i) { o00[i] = 0.f; o01[i] = 0.f; o10[i] = 0.f; o11[i] = 0.f; }
  float l0 = 0.f, l1 = 0.f;

  // prologue: K(g) chunk0 (frags 0-3) — the only cross-tile registers
  bf16x8 kc00, kc01, kc02, kc03;
  {
    const unsigned short* K0 = KbL + (size_t)g * TILE_ELEMS;
    kc00 = *(const bf16x8*)(K0);
    kc01 = *(const bf16x8*)(K0 + 512);
    kc02 = *(const bf16x8*)(K0 + 1024);
    kc03 = *(const bf16x8*)(K0 + 1536);
  }

  for (int tt = 0; tt < NTILES / 2; ++tt) {
    const int t = g + 2 * tt;
    const int tn = (tt + 1 < NTILES / 2) ? t + 2 : t;
    const unsigned short* Kt = KbL + (size_t)t * TILE_ELEMS;
    const unsigned short* Vt = VbL + (size_t)t * TILE_ELEMS;

    // issue K chunk1 + all V fragments (fly under the 16 QK MFMAs)
    bf16x8 kc10 = *(const bf16x8*)(Kt + 2048);
    bf16x8 kc11 = *(const bf16x8*)(Kt + 2560);
    bf16x8 kc12 = *(const bf16x8*)(Kt + 3072);
    bf16x8 kc13 = *(const bf16x8*)(Kt + 3584);
    bf16x8 vc00 = *(const bf16x8*)(Vt);
    bf16x8 vc01 = *(const bf16x8*)(Vt + 512);
    bf16x8 vc02 = *(const bf16x8*)(Vt + 1024);
    bf16x8 vc03 = *(const bf16x8*)(Vt + 1536);
    bf16x8 vc10 = *(const bf16x8*)(Vt + 2048);
    bf16x8 vc11 = *(const bf16x8*)(Vt + 2560);
    bf16x8 vc12 = *(const bf16x8*)(Vt + 3072);
    bf16x8 vc13 = *(const bf16x8*)(Vt + 3584);

    // ---- QK chunk0: both q-groups share kc0* ----
    f32x16 s00, s01, s10, s11;
#pragma unroll
    for (int i = 0; i < 16; ++i) { s00[i] = 0.f; s01[i] = 0.f; s10[i] = 0.f; s11[i] = 0.f; }
    __builtin_amdgcn_s_setprio(1);
    s00 = __builtin_amdgcn_mfma_f32_32x32x16_bf16(kc00, qf0[0], s00, 0, 0, 0);
    s01 = __builtin_amdgcn_mfma_f32_32x32x16_bf16(kc01, qf0[0], s01, 0, 0, 0);
    s10 = __builtin_amdgcn_mfma_f32_32x32x16_bf16(kc00, qf1[0], s10, 0, 0, 0);
    s11 = __builtin_amdgcn_mfma_f32_32x32x16_bf16(kc01, qf1[0], s11, 0, 0, 0);
    s00 = __builtin_amdgcn_mfma_f32_32x32x16_bf16(kc02, qf0[1], s00, 0, 0, 0);
    s01 = __builtin_amdgcn_mfma_f32_32x32x16_bf16(kc03, qf0[1], s01, 0, 0, 0);
    s10 = __builtin_amdgcn_mfma_f32_32x32x16_bf16(kc02, qf1[1], s10, 0, 0, 0);
    s11 = __builtin_amdgcn_mfma_f32_32x32x16_bf16(kc03, qf1[1], s11, 0, 0, 0);
    // ---- QK chunk1 ----
    s00 = __builtin_amdgcn_mfma_f32_32x32x16_bf16(kc10, qf0[2], s00, 0, 0, 0);
    s01 = __builtin_amdgcn_mfma_f32_32x32x16_bf16(kc11, qf0[2], s01, 0, 0, 0);
    s10 = __builtin_amdgcn_mfma_f32_32x32x16_bf16(kc10, qf1[2], s10, 0, 0, 0);
    s11 = __builtin_amdgcn_mfma_f32_32x32x16_bf16(kc11, qf1[2], s11, 0, 0, 0);
    s00 = __builtin_amdgcn_mfma_f32_32x32x16_bf16(kc12, qf0[3], s00, 0, 0, 0);
    s01 = __builtin_amdgcn_mfma_f32_32x32x16_bf16(kc13, qf0[3], s01, 0, 0, 0);
    s10 = __builtin_amdgcn_mfma_f32_32x32x16_bf16(kc12, qf1[3], s10, 0, 0, 0);
    s11 = __builtin_amdgcn_mfma_f32_32x32x16_bf16(kc13, qf1[3], s11, 0, 0, 0);
    __builtin_amdgcn_s_setprio(0);

    // prefetch next tile's K chunk0 (window: SM g0 + PV g0 + SM g1)
    {
      const unsigned short* Kn = KbL + (size_t)tn * TILE_ELEMS;
      kc00 = *(const bf16x8*)(Kn);
      kc01 = *(const bf16x8*)(Kn + 512);
      kc02 = *(const bf16x8*)(Kn + 1024);
      kc03 = *(const bf16x8*)(Kn + 1536);
    }

    // ---- group 0: softmax + PV ; group 1: softmax + PV ----
    SM_PV(s00, s01, o00, o01, l0);
    SM_PV(s10, s11, o10, o11, l1);
  }

  // ---- merge kv-halves in LDS; g==0 waves normalize + store ----
  float la0 = xsum32(l0), la1 = xsum32(l1);
  float* Ow = &Osh[(qw * 64 + lane) * 68];
  if (g == 1) {
#pragma unroll
    for (int rg = 0; rg < 4; ++rg) {
      *(float4*)(Ow + rg * 4)      = (float4){o00[rg*4+0], o00[rg*4+1], o00[rg*4+2], o00[rg*4+3]};
      *(float4*)(Ow + 16 + rg * 4) = (float4){o01[rg*4+0], o01[rg*4+1], o01[rg*4+2], o01[rg*4+3]};
      *(float4*)(Ow + 32 + rg * 4) = (float4){o10[rg*4+0], o10[rg*4+1], o10[rg*4+2], o10[rg*4+3]};
      *(float4*)(Ow + 48 + rg * 4) = (float4){o11[rg*4+0], o11[rg*4+1], o11[rg*4+2], o11[rg*4+3]};
    }
    lsh[(qw * 2 + 0) * 64 + lane] = la0;
    lsh[(qw * 2 + 1) * 64 + lane] = la1;
  }
  __syncthreads();
  if (g == 0) {
    const float inv0 = 1.0f / (la0 + lsh[(qw * 2 + 0) * 64 + lane]);
    const float inv1 = 1.0f / (la1 + lsh[(qw * 2 + 1) * 64 + lane]);
    const int qr0 = q0 + ql;
    const int qr1 = q0 + 32 + ql;
    float* orow0 = Og + ((size_t)(b * L_ + qr0) * C_ + c) * H_;
    float* orow1 = Og + ((size_t)(b * L_ + qr1) * C_ + c) * H_;
#pragma unroll
    for (int rg = 0; rg < 4; ++rg) {
      float4 a0 = *(const float4*)(Ow + rg * 4);
      float4 a1 = *(const float4*)(Ow + 16 + rg * 4);
      float4 a2 = *(const float4*)(Ow + 32 + rg * 4);
      float4 a3 = *(const float4*)(Ow + 48 + rg * 4);
      float4 v0, v1, v2, v3;
      v0.x = (o00[rg*4+0] + a0.x) * inv0; v0.y = (o00[rg*4+1] + a0.y) * inv0;
      v0.z = (o00[rg*4+2] + a0.z) * inv0; v0.w = (o00[rg*4+3] + a0.w) * inv0;
      v1.x = (o01[rg*4+0] + a1.x) * inv0; v1.y = (o01[rg*4+1] + a1.y) * inv0;
      v1.z = (o01[rg*4+2] + a1.z) * inv0; v1.w = (o01[rg*4+3] + a1.w) * inv0;
      v2.x = (o10[rg*4+0] + a2.x) * inv1; v2.y = (o10[rg*4+1] + a2.y) * inv1;
      v2.z = (o10[rg*4+2] + a2.z) * inv1; v2.w = (o10[rg*4+3] + a2.w) * inv1;
      v3.x = (o11[rg*4+0] + a3.x) * inv1; v3.y = (o11[rg*4+1] + a3.y) * inv1;
      v3.z = (o11[rg*4+2] + a3.z) * inv1; v3.w = (o11[rg*4+3] + a3.w) * inv1;
      *(float4*)(orow0 + 8 * rg + 4 * u) = v0;
      *(float4*)(orow0 + 32 + 8 * rg + 4 * u) = v1;
      *(float4*)(orow1 + 8 * rg + 4 * u) = v2;
      *(float4*)(orow1 + 32 + 8 * rg + 4 * u) = v3;
    }
  }
}

extern "C" void kernel_launch(void* const* d_in, const int* in_sizes, int n_in,
                              void* d_out, int out_size, void* d_ws, size_t ws_size,
                              hipStream_t stream) {
  const float* Qg = (const float*)d_in[0];
  const float* Kg = (const float*)d_in[1];
  const float* Vg = (const float*)d_in[2];
  float* Og = (float*)d_out;

  unsigned short* Kb = (unsigned short*)d_ws;
  unsigned short* Vb = Kb + (size_t)TENSOR_ELEMS;

  prepack_kernel<<<4096, 256, 0, stream>>>(Kg, Vg, Kb, Vb);

  dim3 grid(NHEADS * (L_ / QBLK));   // 512 blocks of 4 waves, 2 blocks/CU
  dim3 block(NTHREADS);
  attn_fwd_kernel<<<grid, block, 0, stream>>>(Qg, Kb, Vb, Og);
}

// Round 15
// 57.867 us; speedup vs baseline: 4.7978x; 1.1213x over previous
//
#include <hip/hip_runtime.h>
#include <hip/hip_bf16.h>
#include <stdint.h>

#define B_ 2
#define L_ 2048
#define C_ 16
#define D_ 64
#define H_ 64
#define QBLK 128
#define KVBLK 64
#define NTILES 32            // L_/KVBLK
#define NTHREADS 256         // 4 waves = 2 q-positions(64 rows) x 2 kv-groups
#define NHEADS 32            // B_*C_
#define TILE_ELEMS 4096      // KVBLK*64 bf16 elements (8KB)
#define TENSOR_ELEMS (NHEADS * NTILES * TILE_ELEMS)  // 4,194,304

typedef __attribute__((ext_vector_type(8))) short bf16x8;
typedef __attribute__((ext_vector_type(16))) float f32x16;
typedef __attribute__((ext_vector_type(8))) unsigned short u16x8;

__device__ inline unsigned short f2bf(float f) {
  union { float f; unsigned int u; } v; v.f = f;
  unsigned int u = v.u;
  unsigned int r = (u + 0x7FFFu + ((u >> 16) & 1u)) >> 16;  // RNE
  return (unsigned short)r;
}

__device__ inline float fast_exp2(float x) {
#if __has_builtin(__builtin_amdgcn_exp2f)
  return __builtin_amdgcn_exp2f(x);
#else
  return exp2f(x);
#endif
}

__device__ inline unsigned cvt_pk_bf16(float lo, float hi) {
  unsigned r;
  asm("v_cvt_pk_bf16_f32 %0, %1, %2" : "=v"(r) : "v"(lo), "v"(hi));
  return r;
}

__device__ inline void pl32swap(unsigned &x, unsigned &y) {
#if __has_builtin(__builtin_amdgcn_permlane32_swap)
  auto r = __builtin_amdgcn_permlane32_swap(x, y, false, false);
  x = r[0]; y = r[1];
#else
  asm("v_permlane32_swap_b32 %0, %1" : "+v"(x), "+&v"(y));
#endif
}

__device__ inline float xsum32(float v) {
  unsigned x = __float_as_uint(v), y = x;
  pl32swap(x, y);
  return __uint_as_float(x) + __uint_as_float(y);
}

// ---------------- pre-pass ------------------------------------------------
// Both K and V in per-lane FRAGMENT order for direct global->reg MFMA loads:
//  Kb[head][t][frag=ks*2+half][lane][8]:
//      kv-row = half*32+(lane&31), k = ks*16+(lane>>5)*8+j   (j=0..7)
//  Vb[head][t][frag=m*2+half][lane][8]:
//      h-row  = half*32+(lane&31), kv = m*16+(lane>>5)*8+j
__global__ __launch_bounds__(256) void prepack_kernel(
    const float* __restrict__ Kg, const float* __restrict__ Vg,
    unsigned short* __restrict__ Kb, unsigned short* __restrict__ Vb) {
  int idx = blockIdx.x * 256 + threadIdx.x;     // 0 .. 2*524288-1
  if (idx < 524288) {
    int i = idx;
    int lane = i & 63, frag = (i >> 6) & 7, t = (i >> 9) & 31, head = i >> 14;
    int b = head >> 4, c = head & 15;
    int ks = frag >> 1, half = frag & 1;
    int row = half * 32 + (lane & 31);             // kv row
    int kb = ks * 16 + (lane >> 5) * 8;            // d offset
    const float* src = Kg + ((size_t)(b * L_ + t * 64 + row) * C_ + c) * D_ + kb;
    float4 a0 = ((const float4*)src)[0];
    float4 a1 = ((const float4*)src)[1];
    u16x8 pk;
    pk[0] = f2bf(a0.x); pk[1] = f2bf(a0.y); pk[2] = f2bf(a0.z); pk[3] = f2bf(a0.w);
    pk[4] = f2bf(a1.x); pk[5] = f2bf(a1.y); pk[6] = f2bf(a1.z); pk[7] = f2bf(a1.w);
    size_t dst = ((((size_t)(head * 32 + t)) * 8 + frag) * 64 + lane) * 8;
    *(u16x8*)&Kb[dst] = pk;
  } else {
    int i = idx - 524288;
    int lane = i & 63, frag = (i >> 6) & 7, t = (i >> 9) & 31, head = i >> 14;
    int b = head >> 4, c = head & 15;
    int m = frag >> 1, half = frag & 1;
    int h = half * 32 + (lane & 31);               // h row
    int kv0 = m * 16 + (lane >> 5) * 8;            // kv offset
    const float* src = Vg + ((size_t)(b * L_ + t * 64 + kv0) * C_ + c) * H_ + h;
    u16x8 pv;
#pragma unroll
    for (int j = 0; j < 8; ++j) pv[j] = f2bf(src[(size_t)j * C_ * H_]);
    size_t dst = ((((size_t)(head * 32 + t)) * 8 + frag) * 64 + lane) * 8;
    *(u16x8*)&Vb[dst] = pv;
  }
}

// softmax for one q-group: s0 (kv 0-31), s1 (kv 32-63) -> pf[0..3], rowsum L
#define SM(S0, S1, PF, L)                                                         \
  {                                                                               \
    float rst[4];                                                                 \
    _Pragma("unroll")                                                             \
    for (int tq = 0; tq < 4; ++tq) {                                              \
      const int be = ((2 * tq) & 3) * 4;                                          \
      const int bo = ((2 * tq + 1) & 3) * 4;                                      \
      float p0[4], p1[4];                                                         \
      _Pragma("unroll")                                                           \
      for (int r = 0; r < 4; ++r) {                                               \
        float se = (tq < 2) ? S0[be + r] : S1[be + r];                            \
        float so_ = (tq < 2) ? S0[bo + r] : S1[bo + r];                           \
        p0[r] = fast_exp2(se);                                                    \
        p1[r] = fast_exp2(so_);                                                   \
      }                                                                           \
      rst[tq] = ((p0[0] + p0[1]) + (p0[2] + p0[3])) +                             \
                ((p1[0] + p1[1]) + (p1[2] + p1[3]));                              \
      unsigned x0 = cvt_pk_bf16(p0[0], p0[1]);                                    \
      unsigned x1 = cvt_pk_bf16(p0[2], p0[3]);                                    \
      unsigned y0 = cvt_pk_bf16(p1[0], p1[1]);                                    \
      unsigned y1 = cvt_pk_bf16(p1[2], p1[3]);                                    \
      pl32swap(x0, y0);                                                           \
      pl32swap(x1, y1);                                                           \
      union { unsigned wd[4]; bf16x8 v; } pk_;                                    \
      pk_.wd[0] = x0; pk_.wd[1] = x1; pk_.wd[2] = y0; pk_.wd[3] = y1;             \
      PF[tq] = pk_.v;                                                             \
    }                                                                             \
    L += (rst[0] + rst[1]) + (rst[2] + rst[3]);                                   \
  }

// --- flash fwd: 64 q-rows/wave (2 groups share every K/V frag), kv-split x2,
//     strictly chunked transients to fit the 128 arch-VGPR budget ------------
__global__ __launch_bounds__(NTHREADS, 2) void attn_fwd_kernel(
    const float* __restrict__ Qg,
    const unsigned short* __restrict__ Kb,
    const unsigned short* __restrict__ Vb,
    float* __restrict__ Og) {
  __shared__ float Osh[2 * 64 * 68];   // 34.8 KB merge scratch
  __shared__ float lsh[2 * 2 * 64];

  const int tid  = threadIdx.x;
  const int lane = tid & 63;
  const int w    = tid >> 6;      // wave 0..3
  const int qw   = w >> 1;        // q-position 0..1 (64 rows each)
  const int g    = w & 1;         // kv-group: 0 = even tiles, 1 = odd tiles
  const int ql   = lane & 31;
  const int u    = lane >> 5;

  const int bid   = blockIdx.x;
  const int swz   = (bid & 7) * 64 + (bid >> 3);   // XCD-contiguous
  const int head  = swz >> 4;     // 4 heads per XCD -> K/V L2-resident
  const int qtile = swz & 15;
  const int b     = head >> 4;
  const int c     = head & 15;
  const int q0    = qtile * QBLK + qw * 64;

  const unsigned short* KbL = Kb + (size_t)head * NTILES * TILE_ELEMS + lane * 8;
  const unsigned short* VbL = Vb + (size_t)head * NTILES * TILE_ELEMS + lane * 8;

  // Q as B-operand, PRE-SCALED by 1/sqrt(D)*log2(e); 2 groups of 32 q-rows
  const float sc2 = 0.125f * 1.44269504088896340736f;
  bf16x8 qf0[4], qf1[4];
#pragma unroll
  for (int h = 0; h < 2; ++h) {
    const int qr = q0 + h * 32 + ql;
    const float* qrow = Qg + ((size_t)(b * L_ + qr) * C_ + c) * D_;
#pragma unroll
    for (int ks = 0; ks < 4; ++ks) {
      float4 a0 = *(const float4*)(qrow + ks * 16 + u * 8);
      float4 a1 = *(const float4*)(qrow + ks * 16 + u * 8 + 4);
      bf16x8 q8;
      q8[0] = (short)f2bf(a0.x * sc2); q8[1] = (short)f2bf(a0.y * sc2);
      q8[2] = (short)f2bf(a0.z * sc2); q8[3] = (short)f2bf(a0.w * sc2);
      q8[4] = (short)f2bf(a1.x * sc2); q8[5] = (short)f2bf(a1.y * sc2);
      q8[6] = (short)f2bf(a1.z * sc2); q8[7] = (short)f2bf(a1.w * sc2);
      if (h == 0) qf0[ks] = q8; else qf1[ks] = q8;
    }
  }

  f32x16 o00, o01, o10, o11;   // AGPR: O^T acc per group x h-block
#pragma unroll
  for (int i = 0; i < 16; ++i) { o00[i] = 0.f; o01[i] = 0.f; o10[i] = 0.f; o11[i] = 0.f; }
  float l0 = 0.f, l1 = 0.f;

  // prologue: K(g) chunk0 (frags 0-3)
  bf16x8 ka0, ka1, ka2, ka3;
  {
    const unsigned short* K0 = KbL + (size_t)g * TILE_ELEMS;
    ka0 = *(const bf16x8*)(K0);
    ka1 = *(const bf16x8*)(K0 + 512);
    ka2 = *(const bf16x8*)(K0 + 1024);
    ka3 = *(const bf16x8*)(K0 + 1536);
  }

  for (int tt = 0; tt < NTILES / 2; ++tt) {
    const int t = g + 2 * tt;
    const int tn = (tt + 1 < NTILES / 2) ? t + 2 : t;
    const unsigned short* Kt = KbL + (size_t)t * TILE_ELEMS;
    const unsigned short* Vt = VbL + (size_t)t * TILE_ELEMS;
    const unsigned short* Kn = KbL + (size_t)tn * TILE_ELEMS;

    f32x16 s00, s01, s10, s11;   // AGPR: scores per group x kv-half
#pragma unroll
    for (int i = 0; i < 16; ++i) { s00[i] = 0.f; s01[i] = 0.f; s10[i] = 0.f; s11[i] = 0.f; }

    // {load K chunk1 | QK chunk0 x8}
    bf16x8 kb0 = *(const bf16x8*)(Kt + 2048);
    bf16x8 kb1 = *(const bf16x8*)(Kt + 2560);
    bf16x8 kb2 = *(const bf16x8*)(Kt + 3072);
    bf16x8 kb3 = *(const bf16x8*)(Kt + 3584);
    __builtin_amdgcn_s_setprio(1);
    s00 = __builtin_amdgcn_mfma_f32_32x32x16_bf16(ka0, qf0[0], s00, 0, 0, 0);
    s01 = __builtin_amdgcn_mfma_f32_32x32x16_bf16(ka1, qf0[0], s01, 0, 0, 0);
    s10 = __builtin_amdgcn_mfma_f32_32x32x16_bf16(ka0, qf1[0], s10, 0, 0, 0);
    s11 = __builtin_amdgcn_mfma_f32_32x32x16_bf16(ka1, qf1[0], s11, 0, 0, 0);
    s00 = __builtin_amdgcn_mfma_f32_32x32x16_bf16(ka2, qf0[1], s00, 0, 0, 0);
    s01 = __builtin_amdgcn_mfma_f32_32x32x16_bf16(ka3, qf0[1], s01, 0, 0, 0);
    s10 = __builtin_amdgcn_mfma_f32_32x32x16_bf16(ka2, qf1[1], s10, 0, 0, 0);
    s11 = __builtin_amdgcn_mfma_f32_32x32x16_bf16(ka3, qf1[1], s11, 0, 0, 0);
    __builtin_amdgcn_s_setprio(0);

    // {load V chunk0 (reusing ka regs) | QK chunk1 x8}
    ka0 = *(const bf16x8*)(Vt);
    ka1 = *(const bf16x8*)(Vt + 512);
    ka2 = *(const bf16x8*)(Vt + 1024);
    ka3 = *(const bf16x8*)(Vt + 1536);
    __builtin_amdgcn_s_setprio(1);
    s00 = __builtin_amdgcn_mfma_f32_32x32x16_bf16(kb0, qf0[2], s00, 0, 0, 0);
    s01 = __builtin_amdgcn_mfma_f32_32x32x16_bf16(kb1, qf0[2], s01, 0, 0, 0);
    s10 = __builtin_amdgcn_mfma_f32_32x32x16_bf16(kb0, qf1[2], s10, 0, 0, 0);
    s11 = __builtin_amdgcn_mfma_f32_32x32x16_bf16(kb1, qf1[2], s11, 0, 0, 0);
    s00 = __builtin_amdgcn_mfma_f32_32x32x16_bf16(kb2, qf0[3], s00, 0, 0, 0);
    s01 = __builtin_amdgcn_mfma_f32_32x32x16_bf16(kb3, qf0[3], s01, 0, 0, 0);
    s10 = __builtin_amdgcn_mfma_f32_32x32x16_bf16(kb2, qf1[3], s10, 0, 0, 0);
    s11 = __builtin_amdgcn_mfma_f32_32x32x16_bf16(kb3, qf1[3], s11, 0, 0, 0);
    __builtin_amdgcn_s_setprio(0);

    // {load V chunk1 (reusing kb regs) | softmax g0, g1}
    kb0 = *(const bf16x8*)(Vt + 2048);
    kb1 = *(const bf16x8*)(Vt + 2560);
    kb2 = *(const bf16x8*)(Vt + 3072);
    kb3 = *(const bf16x8*)(Vt + 3584);
    bf16x8 pf0[4], pf1[4];
    SM(s00, s01, pf0, l0);
    SM(s10, s11, pf1, l1);

    // {PV chunk0 x8}  (V chunk0 in ka*, pf[0..1])
    __builtin_amdgcn_s_setprio(1);
    o00 = __builtin_amdgcn_mfma_f32_32x32x16_bf16(ka0, pf0[0], o00, 0, 0, 0);
    o01 = __builtin_amdgcn_mfma_f32_32x32x16_bf16(ka1, pf0[0], o01, 0, 0, 0);
    o10 = __builtin_amdgcn_mfma_f32_32x32x16_bf16(ka0, pf1[0], o10, 0, 0, 0);
    o11 = __builtin_amdgcn_mfma_f32_32x32x16_bf16(ka1, pf1[0], o11, 0, 0, 0);
    o00 = __builtin_amdgcn_mfma_f32_32x32x16_bf16(ka2, pf0[1], o00, 0, 0, 0);
    o01 = __builtin_amdgcn_mfma_f32_32x32x16_bf16(ka3, pf0[1], o01, 0, 0, 0);
    o10 = __builtin_amdgcn_mfma_f32_32x32x16_bf16(ka2, pf1[1], o10, 0, 0, 0);
    o11 = __builtin_amdgcn_mfma_f32_32x32x16_bf16(ka3, pf1[1], o11, 0, 0, 0);
    __builtin_amdgcn_s_setprio(0);

    // {load next-tile K chunk0 (reusing ka regs) | PV chunk1 x8}
    ka0 = *(const bf16x8*)(Kn);
    ka1 = *(const bf16x8*)(Kn + 512);
    ka2 = *(const bf16x8*)(Kn + 1024);
    ka3 = *(const bf16x8*)(Kn + 1536);
    __builtin_amdgcn_s_setprio(1);
    o00 = __builtin_amdgcn_mfma_f32_32x32x16_bf16(kb0, pf0[2], o00, 0, 0, 0);
    o01 = __builtin_amdgcn_mfma_f32_32x32x16_bf16(kb1, pf0[2], o01, 0, 0, 0);
    o10 = __builtin_amdgcn_mfma_f32_32x32x16_bf16(kb0, pf1[2], o10, 0, 0, 0);
    o11 = __builtin_amdgcn_mfma_f32_32x32x16_bf16(kb1, pf1[2], o11, 0, 0, 0);
    o00 = __builtin_amdgcn_mfma_f32_32x32x16_bf16(kb2, pf0[3], o00, 0, 0, 0);
    o01 = __builtin_amdgcn_mfma_f32_32x32x16_bf16(kb3, pf0[3], o01, 0, 0, 0);
    o10 = __builtin_amdgcn_mfma_f32_32x32x16_bf16(kb2, pf1[3], o10, 0, 0, 0);
    o11 = __builtin_amdgcn_mfma_f32_32x32x16_bf16(kb3, pf1[3], o11, 0, 0, 0);
    __builtin_amdgcn_s_setprio(0);
  }

  // ---- merge kv-halves in LDS; g==0 waves normalize + store ----
  float la0 = xsum32(l0), la1 = xsum32(l1);
  float* Ow = &Osh[(qw * 64 + lane) * 68];
  if (g == 1) {
#pragma unroll
    for (int rg = 0; rg < 4; ++rg) {
      *(float4*)(Ow + rg * 4)      = (float4){o00[rg*4+0], o00[rg*4+1], o00[rg*4+2], o00[rg*4+3]};
      *(float4*)(Ow + 16 + rg * 4) = (float4){o01[rg*4+0], o01[rg*4+1], o01[rg*4+2], o01[rg*4+3]};
      *(float4*)(Ow + 32 + rg * 4) = (float4){o10[rg*4+0], o10[rg*4+1], o10[rg*4+2], o10[rg*4+3]};
      *(float4*)(Ow + 48 + rg * 4) = (float4){o11[rg*4+0], o11[rg*4+1], o11[rg*4+2], o11[rg*4+3]};
    }
    lsh[(qw * 2 + 0) * 64 + lane] = la0;
    lsh[(qw * 2 + 1) * 64 + lane] = la1;
  }
  __syncthreads();
  if (g == 0) {
    const float inv0 = 1.0f / (la0 + lsh[(qw * 2 + 0) * 64 + lane]);
    const float inv1 = 1.0f / (la1 + lsh[(qw * 2 + 1) * 64 + lane]);
    const int qr0 = q0 + ql;
    const int qr1 = q0 + 32 + ql;
    float* orow0 = Og + ((size_t)(b * L_ + qr0) * C_ + c) * H_;
    float* orow1 = Og + ((size_t)(b * L_ + qr1) * C_ + c) * H_;
#pragma unroll
    for (int rg = 0; rg < 4; ++rg) {
      float4 a0 = *(const float4*)(Ow + rg * 4);
      float4 a1 = *(const float4*)(Ow + 16 + rg * 4);
      float4 a2 = *(const float4*)(Ow + 32 + rg * 4);
      float4 a3 = *(const float4*)(Ow + 48 + rg * 4);
      float4 v0, v1, v2, v3;
      v0.x = (o00[rg*4+0] + a0.x) * inv0; v0.y = (o00[rg*4+1] + a0.y) * inv0;
      v0.z = (o00[rg*4+2] + a0.z) * inv0; v0.w = (o00[rg*4+3] + a0.w) * inv0;
      v1.x = (o01[rg*4+0] + a1.x) * inv0; v1.y = (o01[rg*4+1] + a1.y) * inv0;
      v1.z = (o01[rg*4+2] + a1.z) * inv0; v1.w = (o01[rg*4+3] + a1.w) * inv0;
      v2.x = (o10[rg*4+0] + a2.x) * inv1; v2.y = (o10[rg*4+1] + a2.y) * inv1;
      v2.z = (o10[rg*4+2] + a2.z) * inv1; v2.w = (o10[rg*4+3] + a2.w) * inv1;
      v3.x = (o11[rg*4+0] + a3.x) * inv1; v3.y = (o11[rg*4+1] + a3.y) * inv1;
      v3.z = (o11[rg*4+2] + a3.z) * inv1; v3.w = (o11[rg*4+3] + a3.w) * inv1;
      *(float4*)(orow0 + 8 * rg + 4 * u) = v0;
      *(float4*)(orow0 + 32 + 8 * rg + 4 * u) = v1;
      *(float4*)(orow1 + 8 * rg + 4 * u) = v2;
      *(float4*)(orow1 + 32 + 8 * rg + 4 * u) = v3;
    }
  }
}

extern "C" void kernel_launch(void* const* d_in, const int* in_sizes, int n_in,
                              void* d_out, int out_size, void* d_ws, size_t ws_size,
                              hipStream_t stream) {
  const float* Qg = (const float*)d_in[0];
  const float* Kg = (const float*)d_in[1];
  const float* Vg = (const float*)d_in[2];
  float* Og = (float*)d_out;

  unsigned short* Kb = (unsigned short*)d_ws;
  unsigned short* Vb = Kb + (size_t)TENSOR_ELEMS;

  prepack_kernel<<<4096, 256, 0, stream>>>(Kg, Vg, Kb, Vb);

  dim3 grid(NHEADS * (L_ / QBLK));   // 512 blocks of 4 waves, 2 blocks/CU
  dim3 block(NTHREADS);
  attn_fwd_kernel<<<grid, block, 0, stream>>>(Qg, Kb, Vb, Og);
}